// Round 3
// baseline (82.109 us; speedup 1.0000x reference)
//
#include <hip/hip_runtime.h>

// y[b,o] = sum_i x[b,i] * (wp[i,o] - wn[i,o]) + (bp[o] - bn[o])
// (G_OFF / k_cond / K_V cancel exactly in the differential-pair readout)
//
// v3: floor-discriminator. v1->v2 inner-loop redesign moved dur_us by only
// +1.2 us (tracking the +8 MB ws traffic), implying the timed window is
// ~41 us ws-poison fill + ~30 us harness reset dispatches + ~7 us us.
// This version removes the last modeled kernel-side slack:
//  - w streamed straight from global (16 KB w-tile is L1-resident; 8 lanes
//    share each 32B chunk) with explicit A/B register pipeline; wp-wn
//    computed on the fly (same fp32 math -> absmax must stay 0.03125).
//  - LDS per kk drops 4->2 ds_read_b128: k-loop flips from LDS-pipe-bound
//    (192 cy/CU/kk) to VALU-bound (~144 cy/SIMD/kk). Partial ~2.6->~2.0 us.
//  - reduce unchanged (8 MB bf16 ws round-trip, ~1.5 us).
// If dur_us stays 77-79: declare harness-floor roofline next round.

#define NB   128
#define NIN  1024
#define NOUT 1024

#define OT   64              // output cols per block
#define KC   32              // k-chunk per block
#define NKS  (NIN / KC)      // 32 K-split slices
#define XS   132             // xs row stride (floats): rows 16B-aligned

__device__ __forceinline__ unsigned short f32_to_bf16_rne(float f) {
    union { float f; unsigned u; } c; c.f = f;
    unsigned u = c.u + 0x7FFFu + ((c.u >> 16) & 1u);   // round-to-nearest-even
    return (unsigned short)(u >> 16);
}
__device__ __forceinline__ float bf16_to_f32(unsigned short h) {
    union { unsigned u; float f; } c; c.u = ((unsigned)h) << 16;
    return c.f;
}

__global__ __launch_bounds__(128) void memr_partial(
    const float* __restrict__ x,  const float* __restrict__ wp,
    const float* __restrict__ wn, unsigned short* __restrict__ ws)
{
    __shared__ float xs[KC * XS];   // 16896 B : x^T [kk][b] (transposed)

    const int t  = threadIdx.x;
    const int o0 = blockIdx.x * OT;
    const int ks = blockIdx.y;
    const int k0 = ks * KC;

    // ---- stage x^T: 1024 coalesced float4 global reads, transposed LDS writes
    #pragma unroll
    for (int r = 0; r < 8; ++r) {
        const int f4 = r * 128 + t;
        const int b  = f4 >> 3;            // 8 float4 per 32-float k-row
        const int q  = f4 & 7;
        const float4 v = *(const float4*)&x[(size_t)b * NIN + k0 + q * 4];
        xs[(q * 4 + 0) * XS + b] = v.x;
        xs[(q * 4 + 1) * XS + b] = v.y;
        xs[(q * 4 + 2) * XS + b] = v.z;
        xs[(q * 4 + 3) * XS + b] = v.w;
    }
    __syncthreads();

    // micro-tile: 8 batch rows x 8 output cols per thread (64 acc VGPRs)
    const int to = t & 7;    // o-octet: o = o0 + to*8 + j
    const int tb = t >> 3;   // b-octet: b = tb*8 + i

    const float* xr  = &xs[tb * 8];
    const float* wpr = wp + (size_t)k0 * NOUT + o0 + to * 8;
    const float* wnr = wn + (size_t)k0 * NOUT + o0 + to * 8;

    float acc[8][8];
    #pragma unroll
    for (int i = 0; i < 8; ++i)
        #pragma unroll
        for (int j = 0; j < 8; ++j) acc[i][j] = 0.f;

    // ---- k-loop: w from global via depth-1 A/B register pipeline.
    // Per kk per lane: 4x global_load_dwordx4 (L1-hot after first touch)
    // + 2x ds_read_b128 (x fragment) + 8 sub + 64 fma.
    float4 Apa = *(const float4*)&wpr[0];
    float4 Apb = *(const float4*)&wpr[4];
    float4 Ana = *(const float4*)&wnr[0];
    float4 Anb = *(const float4*)&wnr[4];

    #pragma unroll 2
    for (int kk = 0; kk < KC; kk += 2) {
        // issue loads for kk+1 (B set) before computing kk
        const size_t ofB = (size_t)(kk + 1) * NOUT;
        float4 Bpa = *(const float4*)&wpr[ofB];
        float4 Bpb = *(const float4*)&wpr[ofB + 4];
        float4 Bna = *(const float4*)&wnr[ofB];
        float4 Bnb = *(const float4*)&wnr[ofB + 4];

        {   // compute kk with A set
            const float4 xa = *(const float4*)&xr[kk * XS];
            const float4 xb = *(const float4*)&xr[kk * XS + 4];
            const float xv[8] = {xa.x, xa.y, xa.z, xa.w, xb.x, xb.y, xb.z, xb.w};
            const float wv[8] = {
                Apa.x - Ana.x, Apa.y - Ana.y, Apa.z - Ana.z, Apa.w - Ana.w,
                Apb.x - Anb.x, Apb.y - Anb.y, Apb.z - Anb.z, Apb.w - Anb.w};
            #pragma unroll
            for (int i = 0; i < 8; ++i)
                #pragma unroll
                for (int j = 0; j < 8; ++j)
                    acc[i][j] += xv[i] * wv[j];
        }

        // issue loads for kk+2 (A set, wrapped at the tail; harmless reload)
        const size_t ofA = (size_t)((kk + 2) & (KC - 1)) * NOUT;
        Apa = *(const float4*)&wpr[ofA];
        Apb = *(const float4*)&wpr[ofA + 4];
        Ana = *(const float4*)&wnr[ofA];
        Anb = *(const float4*)&wnr[ofA + 4];

        {   // compute kk+1 with B set
            const float4 xa = *(const float4*)&xr[(kk + 1) * XS];
            const float4 xb = *(const float4*)&xr[(kk + 1) * XS + 4];
            const float xv[8] = {xa.x, xa.y, xa.z, xa.w, xb.x, xb.y, xb.z, xb.w};
            const float wv[8] = {
                Bpa.x - Bna.x, Bpa.y - Bna.y, Bpa.z - Bna.z, Bpa.w - Bna.w,
                Bpb.x - Bnb.x, Bpb.y - Bnb.y, Bpb.z - Bnb.z, Bpb.w - Bnb.w};
            #pragma unroll
            for (int i = 0; i < 8; ++i)
                #pragma unroll
                for (int j = 0; j < 8; ++j)
                    acc[i][j] += xv[i] * wv[j];
        }
    }

    // ---- store 8x8 partial tile to ws[ks][b][o] as bf16 (2x 8B stores/row)
    unsigned short* wsb = ws + (size_t)ks * NB * NOUT + o0 + to * 8;
    #pragma unroll
    for (int i = 0; i < 8; ++i) {
        const int b = tb * 8 + i;
        ushort4 v0, v1;
        v0.x = f32_to_bf16_rne(acc[i][0]); v0.y = f32_to_bf16_rne(acc[i][1]);
        v0.z = f32_to_bf16_rne(acc[i][2]); v0.w = f32_to_bf16_rne(acc[i][3]);
        v1.x = f32_to_bf16_rne(acc[i][4]); v1.y = f32_to_bf16_rne(acc[i][5]);
        v1.z = f32_to_bf16_rne(acc[i][6]); v1.w = f32_to_bf16_rne(acc[i][7]);
        *(ushort4*)&wsb[(size_t)b * NOUT]     = v0;
        *(ushort4*)&wsb[(size_t)b * NOUT + 4] = v1;
    }
}

__global__ __launch_bounds__(256) void memr_reduce(
    const unsigned short* __restrict__ ws, const float* __restrict__ bp,
    const float* __restrict__ bn, float* __restrict__ out)
{
    // 4 outputs per thread: 8B bf16x4 load per slice (coalesced 512B/wave)
    const int g  = blockIdx.x * 256 + threadIdx.x;  // 0..32767
    const int i4 = g * 4;
    const int o4 = i4 & (NOUT - 1);

    const float4 bpv = *(const float4*)&bp[o4];
    const float4 bnv = *(const float4*)&bn[o4];
    float s0 = bpv.x - bnv.x, s1 = bpv.y - bnv.y;
    float s2 = bpv.z - bnv.z, s3 = bpv.w - bnv.w;

    #pragma unroll
    for (int ks = 0; ks < NKS; ++ks) {
        const ushort4 u = *(const ushort4*)&ws[(size_t)ks * NB * NOUT + i4];
        s0 += bf16_to_f32(u.x); s1 += bf16_to_f32(u.y);
        s2 += bf16_to_f32(u.z); s3 += bf16_to_f32(u.w);
    }
    float4 o; o.x = s0; o.y = s1; o.z = s2; o.w = s3;
    *(float4*)&out[i4] = o;
}

extern "C" void kernel_launch(void* const* d_in, const int* in_sizes, int n_in,
                              void* d_out, int out_size, void* d_ws, size_t ws_size,
                              hipStream_t stream)
{
    const float* x  = (const float*)d_in[0];
    const float* wp = (const float*)d_in[1];
    const float* wn = (const float*)d_in[2];
    const float* bp = (const float*)d_in[3];
    const float* bn = (const float*)d_in[4];
    float* out = (float*)d_out;
    unsigned short* ws = (unsigned short*)d_ws;   // 32*128*1024*2 = 8 MB used

    dim3 g1(NOUT / OT, NKS);       // 16 x 32 = 512 blocks, 2 per CU
    memr_partial<<<g1, 128, 0, stream>>>(x, wp, wn, ws);
    memr_reduce<<<NB * NOUT / 4 / 256, 256, 0, stream>>>(ws, bp, bn, out);
}

// Round 4
// 76.714 us; speedup vs baseline: 1.0703x; 1.0703x over previous
//
#include <hip/hip_runtime.h>

// y[b,o] = sum_i x[b,i] * (wp[i,o] - wn[i,o]) + (bp[o] - bn[o])
// (G_OFF / k_cond / K_V cancel exactly in the differential-pair readout)
//
// v4 = round-0 kernel (best measured: 77.4 us) with ONE change:
//   reduce kernel 64 -> 256 blocks. 64 blocks = 64 CUs = ~1.5 TB/s issue
//   ceiling (10 B/cy/CU) -> 4.5 MB read took ~3.2 us. 256 blocks / 2 outs
//   per thread restores full-chip load issue -> ~0.9 us.
// Partial kernel byte-identical to the 77.4 us baseline (v3's global-w
// streaming regressed +3.5 us: 16x32B L1 requests/wave/kk thrashed L1;
// LDS-staged w is the right structure).

#define NB   128
#define NIN  1024
#define NOUT 1024

#define OT   32              // output cols per block
#define KC   64              // k-chunk per block
#define NKS  (NIN / KC)      // 16 K-split slices
#define XP   65              // xs row stride (odd -> at most 2-way bank alias)

__device__ __forceinline__ unsigned short f32_to_bf16_rne(float f) {
    union { float f; unsigned u; } c; c.f = f;
    unsigned u = c.u + 0x7FFFu + ((c.u >> 16) & 1u);   // round-to-nearest-even
    return (unsigned short)(u >> 16);
}
__device__ __forceinline__ float bf16_to_f32(unsigned short h) {
    union { unsigned u; float f; } c; c.u = ((unsigned)h) << 16;
    return c.f;
}

__global__ __launch_bounds__(128) void memr_partial(
    const float* __restrict__ x,  const float* __restrict__ wp,
    const float* __restrict__ wn, unsigned short* __restrict__ ws)
{
    __shared__ float xs[NB * XP];   // 33280 B : x[0:128][k0:k0+64]
    __shared__ float wd[KC * OT];   //  8192 B : (wp-wn)[k0:k0+64][o0:o0+32]

    const int t  = threadIdx.x;
    const int o0 = blockIdx.x * OT;
    const int ks = blockIdx.y;
    const int k0 = ks * KC;

    // ---- stage x: 2048 float4 coalesced loads, scalar LDS stores
    #pragma unroll
    for (int r = 0; r < 16; ++r) {
        const int f4 = r * 128 + t;
        const int b  = f4 >> 4;           // 16 float4 per 64-float row
        const int q  = f4 & 15;
        const float4 v = *(const float4*)&x[(size_t)b * NIN + k0 + q * 4];
        float* d = &xs[b * XP + q * 4];
        d[0] = v.x; d[1] = v.y; d[2] = v.z; d[3] = v.w;
    }
    // ---- stage wd = wp - wn : 512 float4 each, coalesced
    #pragma unroll
    for (int r = 0; r < 4; ++r) {
        const int f4 = r * 128 + t;
        const int k  = f4 >> 3;           // 8 float4 per 32-float row
        const int q  = f4 & 7;
        const size_t g = (size_t)(k0 + k) * NOUT + o0 + q * 4;
        const float4 p = *(const float4*)&wp[g];
        const float4 n = *(const float4*)&wn[g];
        float4 d4;
        d4.x = p.x - n.x; d4.y = p.y - n.y; d4.z = p.z - n.z; d4.w = p.w - n.w;
        *(float4*)&wd[k * OT + q * 4] = d4;
    }
    __syncthreads();

    // micro-tile: 8 batch rows x 4 output cols per thread (32 acc VGPRs)
    const int tx = t & 7;    // o-quad: o = o0 + tx*4 + j
    const int ty = t >> 3;   // b-octet: b = ty*8 + i

    float acc[8][4];
    #pragma unroll
    for (int i = 0; i < 8; ++i)
        #pragma unroll
        for (int j = 0; j < 4; ++j) acc[i][j] = 0.f;

    const float* xr = &xs[ty * 8 * XP];
    const float* wr = &wd[tx * 4];

    #pragma unroll 8
    for (int k = 0; k < KC; ++k) {
        const float4 w4 = *(const float4*)&wr[k * OT];
        float xv[8];
        #pragma unroll
        for (int i = 0; i < 8; ++i) xv[i] = xr[i * XP + k];
        #pragma unroll
        for (int i = 0; i < 8; ++i) {
            acc[i][0] += xv[i] * w4.x;
            acc[i][1] += xv[i] * w4.y;
            acc[i][2] += xv[i] * w4.z;
            acc[i][3] += xv[i] * w4.w;
        }
    }

    // ---- store partial tile to ws[ks][b][o] as bf16 (8 B per store, coalesced)
    unsigned short* wsb = ws + (size_t)ks * NB * NOUT;
    #pragma unroll
    for (int i = 0; i < 8; ++i) {
        const int b = ty * 8 + i;
        ushort4 v;
        v.x = f32_to_bf16_rne(acc[i][0]);
        v.y = f32_to_bf16_rne(acc[i][1]);
        v.z = f32_to_bf16_rne(acc[i][2]);
        v.w = f32_to_bf16_rne(acc[i][3]);
        *(ushort4*)&wsb[(size_t)b * NOUT + o0 + tx * 4] = v;
    }
}

__global__ __launch_bounds__(256) void memr_reduce(
    const unsigned short* __restrict__ ws, const float* __restrict__ bp,
    const float* __restrict__ bn, float* __restrict__ out)
{
    // 2 outputs per thread, 256 blocks: full-chip load issue for the
    // BW-bound ws read (4B bf16x2 per slice, 256B/wave coalesced)
    const int g  = blockIdx.x * 256 + threadIdx.x;  // 0..65535
    const int i2 = g * 2;
    const int o2 = i2 & (NOUT - 1);

    float s0 = bp[o2]     - bn[o2];
    float s1 = bp[o2 + 1] - bn[o2 + 1];

    #pragma unroll
    for (int ks = 0; ks < NKS; ++ks) {
        const unsigned u = *(const unsigned*)&ws[(size_t)ks * NB * NOUT + i2];
        s0 += bf16_to_f32((unsigned short)(u & 0xffffu));
        s1 += bf16_to_f32((unsigned short)(u >> 16));
    }
    float2 o; o.x = s0; o.y = s1;
    *(float2*)&out[i2] = o;
}

extern "C" void kernel_launch(void* const* d_in, const int* in_sizes, int n_in,
                              void* d_out, int out_size, void* d_ws, size_t ws_size,
                              hipStream_t stream)
{
    const float* x  = (const float*)d_in[0];
    const float* wp = (const float*)d_in[1];
    const float* wn = (const float*)d_in[2];
    const float* bp = (const float*)d_in[3];
    const float* bn = (const float*)d_in[4];
    float* out = (float*)d_out;
    unsigned short* ws = (unsigned short*)d_ws;   // 16*128*1024*2 = 4 MB used

    dim3 g1(NOUT / OT, NKS);       // 32 x 16 = 512 blocks
    memr_partial<<<g1, 128, 0, stream>>>(x, wp, wn, ws);
    memr_reduce<<<NB * NOUT / 2 / 256, 256, 0, stream>>>(ws, bp, bn, out);
}